// Round 2
// baseline (699.826 us; speedup 1.0000x reference)
//
#include <hip/hip_runtime.h>

// LIF multistep: T=4, VTHR=1.0, TAU=0.5, hard reset.
// x: (T, 32, 512, 1024) fp32.  Outputs: spikes (T*N), mems (T*N) concatenated.
// N = 2^24 elements per timestep, n4 = 2^22 float4 groups.
// Memory-bound: 256 MiB read + 512 MiB write -> ~128 us roofline at 6.3 TB/s.
//
// R2 changes vs R1 (dur 674.6; attribution: kernel ~170 us + ~500 us fixed
// harness reset cost):
//  - x loads back to CACHED path (L2, ~200cy) -- NT loads bought nothing
//    (read-once, and NT stores already keep L2 clean). m13's 6.29 TB/s
//    copy uses cached loads.
//  - NT kept on stores only (537 MB write-once must not thrash L2/LLC).
//  - 4 float4 per thread per stream (two hoisted pairs -> VGPR stays
//    ~R1 level, no spill), 4096 blocks.
//  - Wave-uniform full-tile fast path: zero per-access predicates
//    (n4 = 2^22 divides exactly into 1024-float4 tiles); generic tail
//    retained for shape safety.

#define LIF_T 4
#define BLOCK 256
#define VPT   4                   // float4 slots per thread per stream
#define TILE  (BLOCK * VPT)       // 1024 float4 groups per block

typedef float f32x4 __attribute__((ext_vector_type(4)));

__device__ __forceinline__ void lif_step(f32x4& v, const f32x4 xt,
                                         f32x4& s_out, f32x4& u_out) {
    const float VTHR = 1.0f;
    const float TAU  = 0.5f;
    f32x4 u = v + xt;              // integrate
    f32x4 s;
#pragma unroll
    for (int c = 0; c < 4; ++c) {
        bool fire = u[c] > VTHR;   // ZIF forward = Heaviside (strict >)
        s[c] = fire ? 1.f : 0.f;
        u[c] = fire ? 0.f : u[c];  // hard reset, exact zero
    }
    s_out = s;
    u_out = u;                     // post-reset, pre-decay (per reference)
    v = u * TAU;                   // decay carried state
}

__global__ __launch_bounds__(BLOCK) void lif_kernel(
    const f32x4* __restrict__ x,
    f32x4* __restrict__ spikes,
    f32x4* __restrict__ mems,
    long n4)   // float4 groups per timestep
{
    const long base = (long)blockIdx.x * TILE + threadIdx.x;

    if ((long)(blockIdx.x + 1) * TILE <= n4) {
        // -------- fast path: full tile, no per-access predicates --------
        // Process slot-pairs {0,1} then {2,3}: 8 loads in flight per pair,
        // VGPR pressure bounded.
#pragma unroll
        for (int h = 0; h < VPT / 2; ++h) {
            const size_t i0 = (size_t)base + (2 * h)     * BLOCK;
            const size_t i1 = (size_t)base + (2 * h + 1) * BLOCK;

            f32x4 xa[LIF_T], xb[LIF_T];
#pragma unroll
            for (int t = 0; t < LIF_T; ++t) {
                xa[t] = x[(size_t)t * n4 + i0];   // cached loads
                xb[t] = x[(size_t)t * n4 + i1];
            }

            f32x4 va = {0.f, 0.f, 0.f, 0.f};
            f32x4 vb = {0.f, 0.f, 0.f, 0.f};
#pragma unroll
            for (int t = 0; t < LIF_T; ++t) {
                f32x4 s, u;
                lif_step(va, xa[t], s, u);
                __builtin_nontemporal_store(s, &spikes[(size_t)t * n4 + i0]);
                __builtin_nontemporal_store(u, &mems  [(size_t)t * n4 + i0]);
                lif_step(vb, xb[t], s, u);
                __builtin_nontemporal_store(s, &spikes[(size_t)t * n4 + i1]);
                __builtin_nontemporal_store(u, &mems  [(size_t)t * n4 + i1]);
            }
        }
    } else {
        // -------- tail: never taken for the fixed bench shape --------
        for (int k = 0; k < VPT; ++k) {
            long i = base + (long)k * BLOCK;
            if (i >= n4) continue;
            f32x4 v = {0.f, 0.f, 0.f, 0.f};
            for (int t = 0; t < LIF_T; ++t) {
                f32x4 s, u;
                lif_step(v, x[(size_t)t * n4 + i], s, u);
                spikes[(size_t)t * n4 + i] = s;
                mems[(size_t)t * n4 + i]   = u;
            }
        }
    }
}

extern "C" void kernel_launch(void* const* d_in, const int* in_sizes, int n_in,
                              void* d_out, int out_size, void* d_ws, size_t ws_size,
                              hipStream_t stream) {
    const float* x = (const float*)d_in[0];
    float* out = (float*)d_out;

    long total = (long)in_sizes[0];       // T * N
    long N = total / LIF_T;               // elements per timestep
    long n4 = N / 4;                      // float4 groups per timestep

    f32x4* spikes = (f32x4*)out;                    // first T*N floats
    f32x4* mems   = (f32x4*)(out + total);          // next T*N floats

    long grid = (n4 + TILE - 1) / TILE;   // 4096 blocks for the bench shape

    lif_kernel<<<dim3((unsigned)grid), dim3(BLOCK), 0, stream>>>(
        (const f32x4*)x, spikes, mems, n4);
}